// Round 1
// baseline (521.995 us; speedup 1.0000x reference)
//
#include <hip/hip_runtime.h>
#include <math.h>

// Sizes fixed by the reference
#define NB    64
#define CIN   256
#define HH    28
#define WW    28
#define HW    784          // 28*28
#define INTER 128
#define QT    64           // q rows per block (kernel 2)
#define KT    64           // k cols per tile  (kernel 2)

// ---------------------------------------------------------------------------
// Kernel 1: projections.
//   Y[n,i,p]  = sum_c Wq[i,c] * X[n,c,p] + bq[i]      (i in [0,128))
//   vAll[n,p] = sum_c Wv[c]   * X[n,c,p] + bv
// One thread per (n,p) column; blockIdx.y picks a 32-wide i-slab.
// Wq reads are wave-uniform -> scalar loads; X reads coalesced over p.
// ---------------------------------------------------------------------------
__global__ __launch_bounds__(256) void proj_kernel(
    const float* __restrict__ x,
    const float* __restrict__ Wq, const float* __restrict__ bq,
    const float* __restrict__ Wv, const float* __restrict__ bv,
    float* __restrict__ Y, float* __restrict__ vAll)
{
    const int t    = threadIdx.x;
    const int gcol = blockIdx.x * 256 + t;          // 196*256 == 50176 exactly
    const int n    = gcol / HW;
    const int p    = gcol - n * HW;
    const int i0   = blockIdx.y * 32;
    const float* xcol = x + (size_t)n * (CIN * HW) + p;

    float acc[32];
#pragma unroll
    for (int i = 0; i < 32; ++i) acc[i] = bq[i0 + i];
    float vacc = bv[0];

    for (int cc = 0; cc < CIN; cc += 8) {
        float xc[8];
#pragma unroll
        for (int j = 0; j < 8; ++j) xc[j] = xcol[(cc + j) * HW];
#pragma unroll
        for (int i = 0; i < 32; ++i) {
            const float* wrow = Wq + (i0 + i) * CIN + cc;
#pragma unroll
            for (int j = 0; j < 8; ++j) acc[i] = fmaf(wrow[j], xc[j], acc[i]);
        }
        if (blockIdx.y == 0) {
#pragma unroll
            for (int j = 0; j < 8; ++j) vacc = fmaf(Wv[cc + j], xc[j], vacc);
        }
    }
#pragma unroll
    for (int i = 0; i < 32; ++i)
        Y[((size_t)n * INTER + i0 + i) * HW + p] = acc[i];
    if (blockIdx.y == 0) vAll[gcol] = vacc;
}

// ---------------------------------------------------------------------------
// Kernel 2: fused attention with online softmax.
//   scores[q,k] = (1/sqrt(128)) * sum_i Y[n,i,q] * Y[idx,i,k]
//   mask[n,q]   = sum_k softmax(scores)[k] * vAll[idx,k]
// Block = (n, 64-q-row tile). K streamed in 64-col LDS tiles.
// Thread micro-tile: 4q x 4k; 16 lanes (t&15) share one 4-q group and
// reduce softmax stats via shfl_xor(1,2,4,8).
// LDS: Qs[128][64] + Ks[128][64] = 64 KiB exactly (no pad needed:
// Q-read is 4-address broadcast, K-read is 2-way aliased = free).
// ---------------------------------------------------------------------------
__global__ __launch_bounds__(256) void attn_kernel(
    const float* __restrict__ Y, const float* __restrict__ vAll,
    const int* __restrict__ index, float* __restrict__ maskbuf)
{
    __shared__ float Qs[INTER * QT];
    __shared__ float Ks[INTER * KT];

    const int n   = blockIdx.x;
    const int q0  = blockIdx.y * QT;
    const int t   = threadIdx.x;
    const int idx = index[n];
    const float scale = 0.08838834764831845f;   // 1/sqrt(128)

    const float* Qg = Y + (size_t)n   * (INTER * HW);
    const float* Kg = Y + (size_t)idx * (INTER * HW);
    const float* Vg = vAll + (size_t)idx * HW;

    // load + pre-scale Q tile: Qs[i][q]
    for (int e = t; e < INTER * QT; e += 256) {
        const int i = e >> 6, q = e & 63;
        const int gq = q0 + q;
        Qs[i * QT + q] = (gq < HW) ? Qg[i * HW + gq] * scale : 0.0f;
    }

    const int qg = t >> 4;   // 0..15 -> q rows q0 + 4*qg + [0,4)
    const int ks = t & 15;   // 0..15 -> k cols k0 + 4*ks + [0,4)

    float ml[4], ll[4], oo[4];
#pragma unroll
    for (int a = 0; a < 4; ++a) { ml[a] = -1e30f; ll[a] = 0.0f; oo[a] = 0.0f; }

    const int NKT = (HW + KT - 1) / KT;          // 13 (last tile masked)
    for (int kt = 0; kt < NKT; ++kt) {
        const int k0 = kt * KT;
        __syncthreads();
        for (int e = t; e < INTER * KT; e += 256) {
            const int i = e >> 6, k = e & 63;
            const int gk = k0 + k;
            Ks[i * KT + k] = (gk < HW) ? Kg[i * HW + gk] : 0.0f;
        }
        __syncthreads();

        float s[4][4];
#pragma unroll
        for (int a = 0; a < 4; ++a)
#pragma unroll
            for (int b = 0; b < 4; ++b) s[a][b] = 0.0f;

        for (int i = 0; i < INTER; ++i) {
            const float4 qv = *(const float4*)(Qs + i * QT + (qg << 2));
            const float4 kv = *(const float4*)(Ks + i * KT + (ks << 2));
            s[0][0] = fmaf(qv.x, kv.x, s[0][0]); s[0][1] = fmaf(qv.x, kv.y, s[0][1]);
            s[0][2] = fmaf(qv.x, kv.z, s[0][2]); s[0][3] = fmaf(qv.x, kv.w, s[0][3]);
            s[1][0] = fmaf(qv.y, kv.x, s[1][0]); s[1][1] = fmaf(qv.y, kv.y, s[1][1]);
            s[1][2] = fmaf(qv.y, kv.z, s[1][2]); s[1][3] = fmaf(qv.y, kv.w, s[1][3]);
            s[2][0] = fmaf(qv.z, kv.x, s[2][0]); s[2][1] = fmaf(qv.z, kv.y, s[2][1]);
            s[2][2] = fmaf(qv.z, kv.z, s[2][2]); s[2][3] = fmaf(qv.z, kv.w, s[2][3]);
            s[3][0] = fmaf(qv.w, kv.x, s[3][0]); s[3][1] = fmaf(qv.w, kv.y, s[3][1]);
            s[3][2] = fmaf(qv.w, kv.z, s[3][2]); s[3][3] = fmaf(qv.w, kv.w, s[3][3]);
        }

        // mask padded k columns (only last tile has any)
#pragma unroll
        for (int b = 0; b < 4; ++b) {
            if (k0 + (ks << 2) + b >= HW) {
                s[0][b] = -1e30f; s[1][b] = -1e30f;
                s[2][b] = -1e30f; s[3][b] = -1e30f;
            }
        }

        // v values for this thread's 4 k's (clamped addr; clamped lanes are
        // fully masked so the values are never used)
        const int kvb = k0 + (ks << 2);
        const float4 vv = *(const float4*)(Vg + min(kvb, HW - 4));

        // online softmax update, per q row
#pragma unroll
        for (int a = 0; a < 4; ++a) {
            float tm = fmaxf(fmaxf(s[a][0], s[a][1]), fmaxf(s[a][2], s[a][3]));
#pragma unroll
            for (int m = 1; m <= 8; m <<= 1) tm = fmaxf(tm, __shfl_xor(tm, m));
            const float mnew = fmaxf(ml[a], tm);
            const float corr = __expf(ml[a] - mnew);
            const float e0 = __expf(s[a][0] - mnew);
            const float e1 = __expf(s[a][1] - mnew);
            const float e2 = __expf(s[a][2] - mnew);
            const float e3 = __expf(s[a][3] - mnew);
            float ps = e0 + e1 + e2 + e3;
            float pv = e0 * vv.x + e1 * vv.y + e2 * vv.z + e3 * vv.w;
#pragma unroll
            for (int m = 1; m <= 8; m <<= 1) {
                ps += __shfl_xor(ps, m);
                pv += __shfl_xor(pv, m);
            }
            ll[a] = ll[a] * corr + ps;
            oo[a] = oo[a] * corr + pv;
            ml[a] = mnew;
        }
    }

    if (ks == 0) {
#pragma unroll
        for (int a = 0; a < 4; ++a) {
            const int q = q0 + (qg << 2) + a;
            if (q < HW) maskbuf[n * HW + q] = oo[a] / ll[a];
        }
    }
}

// ---------------------------------------------------------------------------
// Kernel 3: bilinear x8 upsample (half-pixel centers, edge clamp == jax's
// weight renormalization for integer upscale) + sigmoid + concat([1-m, m]).
// One thread = 4 consecutive output x's; float4 stores to both channels.
// ---------------------------------------------------------------------------
__global__ __launch_bounds__(256) void upsample_kernel(
    const float* __restrict__ maskbuf, float* __restrict__ out)
{
    const int gid = blockIdx.x * 256 + threadIdx.x;   // 64*224*56 = 802816
    const int n  = gid / (224 * 56);
    const int r  = gid - n * (224 * 56);
    const int oy = r / 56;
    const int xq = r - oy * 56;

    const float iy = (oy + 0.5f) * 0.125f - 0.5f;
    const int   y0 = (int)floorf(iy);
    const float fy = iy - (float)y0;
    const int y0c = max(y0, 0), y1c = min(y0 + 1, HH - 1);
    const float* mrow = maskbuf + n * HW;

    float res[4];
#pragma unroll
    for (int j = 0; j < 4; ++j) {
        const int   ox = (xq << 2) + j;
        const float ix = (ox + 0.5f) * 0.125f - 0.5f;
        const int   x0 = (int)floorf(ix);
        const float fx = ix - (float)x0;
        const int x0c = max(x0, 0), x1c = min(x0 + 1, WW - 1);
        const float v00 = mrow[y0c * WW + x0c], v01 = mrow[y0c * WW + x1c];
        const float v10 = mrow[y1c * WW + x0c], v11 = mrow[y1c * WW + x1c];
        const float m = (v00 * (1.0f - fx) + v01 * fx) * (1.0f - fy)
                      + (v10 * (1.0f - fx) + v11 * fx) * fy;
        res[j] = 1.0f / (1.0f + __expf(-m));
    }

    float4 pos = make_float4(res[0], res[1], res[2], res[3]);
    float4 neg = make_float4(1.0f - res[0], 1.0f - res[1],
                             1.0f - res[2], 1.0f - res[3]);
    const size_t base = (size_t)n * 2 * 50176 + (size_t)oy * 224 + (xq << 2);
    *(float4*)(out + base)         = neg;   // channel 0: 1 - mask
    *(float4*)(out + base + 50176) = pos;   // channel 1: mask
}

// ---------------------------------------------------------------------------
extern "C" void kernel_launch(void* const* d_in, const int* in_sizes, int n_in,
                              void* d_out, int out_size, void* d_ws, size_t ws_size,
                              hipStream_t stream) {
    const float* x     = (const float*)d_in[0];
    // d_in[1] = lam (unused by the reference output)
    const int*   index = (const int*)d_in[2];
    const float* Wq    = (const float*)d_in[3];
    const float* bq    = (const float*)d_in[4];
    const float* Wv    = (const float*)d_in[5];
    const float* bv    = (const float*)d_in[6];
    // d_in[7] = scale_factor (fixed = 8)

    float* out = (float*)d_out;
    // 64*128*784 == 64*2*224*224 == out_size: use d_out as scratch for Y,
    // kernel 3 fully overwrites it afterwards.
    float* Y = out;
    // ws: vAll (64*784 f32) + mask (64*784 f32) = 401,408 B
    float* vAll  = (float*)d_ws;
    float* maskb = vAll + NB * HW;

    proj_kernel<<<dim3(196, 4), 256, 0, stream>>>(x, Wq, bq, Wv, bv, Y, vAll);
    attn_kernel<<<dim3(NB, 13), 256, 0, stream>>>(Y, vAll, index, maskb);
    upsample_kernel<<<3136, 256, 0, stream>>>(maskb, out);
}

// Round 2
// 205.061 us; speedup vs baseline: 2.5456x; 2.5456x over previous
//
#include <hip/hip_runtime.h>
#include <math.h>

// Sizes fixed by the reference
#define NB    64
#define CIN   256
#define HH    28
#define WW    28
#define HW    784          // 28*28
#define INTER 128

typedef __bf16 bf16x8 __attribute__((ext_vector_type(8)));
typedef float  f32x4  __attribute__((ext_vector_type(4)));

// round-to-nearest-even f32 -> bf16 bits
__device__ __forceinline__ unsigned int bfbits(float f) {
    unsigned int u = __builtin_bit_cast(unsigned int, f);
    return (u + 0x7fffu + ((u >> 16) & 1u)) >> 16;
}

// ---------------------------------------------------------------------------
// Kernel 1: projections.
//   Yb[n,p,i] = bf16( S * (sum_c Wq[i,c]*X[n,c,p] + bq[i]) ),  S = 128^(-1/4)
//   vAll[n,p] =        sum_c Wv[c]  *X[n,c,p] + bv
// Pre-scaling by S on BOTH q and k gives scores = QK/sqrt(128) with no
// scaling in the attention kernel. Layout [n][p][i] makes MFMA fragments
// (8 consecutive i for fixed p) contiguous 16B loads.
// ---------------------------------------------------------------------------
__global__ __launch_bounds__(256) void proj_kernel(
    const float* __restrict__ x,
    const float* __restrict__ Wq, const float* __restrict__ bq,
    const float* __restrict__ Wv, const float* __restrict__ bv,
    unsigned short* __restrict__ Yb, float* __restrict__ vAll)
{
    const int t    = threadIdx.x;
    const int gcol = blockIdx.x * 256 + t;          // 196*256 == 50176 exactly
    const int n    = gcol / HW;
    const int p    = gcol - n * HW;
    const int i0   = blockIdx.y * 32;
    const float* xcol = x + (size_t)n * (CIN * HW) + p;

    float acc[32];
#pragma unroll
    for (int i = 0; i < 32; ++i) acc[i] = bq[i0 + i];
    float vacc = bv[0];

    for (int cc = 0; cc < CIN; cc += 8) {
        float xc[8];
#pragma unroll
        for (int j = 0; j < 8; ++j) xc[j] = xcol[(cc + j) * HW];
#pragma unroll
        for (int i = 0; i < 32; ++i) {
            const float* wrow = Wq + (i0 + i) * CIN + cc;
#pragma unroll
            for (int j = 0; j < 8; ++j) acc[i] = fmaf(wrow[j], xc[j], acc[i]);
        }
        if (blockIdx.y == 0) {
#pragma unroll
            for (int j = 0; j < 8; ++j) vacc = fmaf(Wv[cc + j], xc[j], vacc);
        }
    }

    const float S = 0.29730177875068026f;   // 128^(-1/4)
    unsigned int wpk[16];
#pragma unroll
    for (int j = 0; j < 16; ++j)
        wpk[j] = bfbits(acc[2 * j] * S) | (bfbits(acc[2 * j + 1] * S) << 16);

    uint4* dst = (uint4*)(Yb + (size_t)gcol * INTER + i0);
    dst[0] = make_uint4(wpk[0],  wpk[1],  wpk[2],  wpk[3]);
    dst[1] = make_uint4(wpk[4],  wpk[5],  wpk[6],  wpk[7]);
    dst[2] = make_uint4(wpk[8],  wpk[9],  wpk[10], wpk[11]);
    dst[3] = make_uint4(wpk[12], wpk[13], wpk[14], wpk[15]);

    if (blockIdx.y == 0) vAll[gcol] = vacc;
}

// ---------------------------------------------------------------------------
// Kernel 2: fused attention, bf16 MFMA scores + in-register online softmax.
// Block = (n, 64-q tile), 4 waves x 16 q each. K streamed in 64-row LDS
// tiles (double-buffered, 2x16 KiB), XOR-swizzled (slot ^= row&7) so both
// the staged ds_write_b128 and the A-fragment ds_read_b128 are bank-balanced.
// Swapped MFMA: D = K_tile * Q  ->  lane holds col q = lane&15, 16 k-values
// (4 acc tiles x 4 regs). Softmax reduce = lane-local + shfl_xor(16,32).
// ---------------------------------------------------------------------------
__global__ __launch_bounds__(256) void attn_kernel(
    const unsigned short* __restrict__ Yb, const float* __restrict__ vAll,
    const int* __restrict__ index, float* __restrict__ maskbuf)
{
    __shared__ unsigned short Ks[2][64 * INTER];   // 2 x 16 KiB

    const int n   = blockIdx.x;
    const int q0  = blockIdx.y * 64;
    const int t   = threadIdx.x;
    const int l   = t & 63;
    const int w   = t >> 6;
    const int idx = index[n];

    const unsigned short* Qg = Yb + (size_t)n   * (HW * INTER);
    const unsigned short* Kg = Yb + (size_t)idx * (HW * INTER);
    const float*          Vg = vAll + (size_t)idx * HW;

    const int ql = l & 15;          // q within wave tile / A-row within k16 tile
    const int g  = (l >> 4) & 3;    // i-group for fragments

    // Q fragments: once per block, kept in VGPRs. q = q0+w*16+ql (clamped),
    // i = ic*32 + g*8 + [0,8)
    const int qrow = min(q0 + w * 16 + ql, HW - 1);
    bf16x8 qf[4];
#pragma unroll
    for (int ic = 0; ic < 4; ++ic)
        qf[ic] = *(const bf16x8*)(Qg + (size_t)qrow * INTER + ic * 32 + g * 8);

    // staging mapping: thread t -> row sr = t>>2 (0..63), 4 slots (t&3)*4+c
    const int sr = t >> 2;
    const int sc = t & 3;

    float4 stg[4];
    {
        const unsigned short* Krow = Kg + (size_t)sr * INTER;   // tile 0, rows valid
#pragma unroll
        for (int c = 0; c < 4; ++c)
            stg[c] = *(const float4*)(Krow + (sc * 4 + c) * 8);
    }
#pragma unroll
    for (int c = 0; c < 4; ++c) {
        const int sl = sc * 4 + c;
        *(float4*)&Ks[0][sr * INTER + ((sl ^ (sr & 7)) << 3)] = stg[c];
    }
    __syncthreads();

    float ml = -1e30f, ll = 0.0f, oo = 0.0f;
    int cur = 0;

    for (int kt = 0; kt < 13; ++kt) {
        const int k0 = kt * 64;
        const int ktlim = (k0 + 64 <= HW) ? 4 : 1;   // last tile: 16 valid k

        // issue next tile's global loads early (hide HBM under MFMA+softmax)
        if (kt < 12) {
            const int rr = min(k0 + 64 + sr, HW - 1);
            const unsigned short* Krow = Kg + (size_t)rr * INTER;
#pragma unroll
            for (int c = 0; c < 4; ++c)
                stg[c] = *(const float4*)(Krow + (sc * 4 + c) * 8);
        }

        // scores: acc[kt16][r] = S[k = k0+kt16*16+g*4+r][q = q0+w*16+ql]
        f32x4 acc[4];
#pragma unroll
        for (int kt16 = 0; kt16 < 4; ++kt16) {
            if (kt16 < ktlim) {
                acc[kt16] = (f32x4){0.0f, 0.0f, 0.0f, 0.0f};
#pragma unroll
                for (int ic = 0; ic < 4; ++ic) {
                    const int krow = kt16 * 16 + ql;
                    const int sl   = ic * 4 + g;
                    const bf16x8 af = *(const bf16x8*)
                        &Ks[cur][krow * INTER + ((sl ^ (krow & 7)) << 3)];
                    acc[kt16] = __builtin_amdgcn_mfma_f32_16x16x32_bf16(
                        af, qf[ic], acc[kt16], 0, 0, 0);
                }
            }
        }

        // online softmax update for this lane's q
        float tm = -1e30f;
#pragma unroll
        for (int kt16 = 0; kt16 < 4; ++kt16)
            if (kt16 < ktlim) {
                tm = fmaxf(tm, fmaxf(fmaxf(acc[kt16][0], acc[kt16][1]),
                                     fmaxf(acc[kt16][2], acc[kt16][3])));
            }
        tm = fmaxf(tm, __shfl_xor(tm, 16));
        tm = fmaxf(tm, __shfl_xor(tm, 32));

        const float mnew = fmaxf(ml, tm);
        const float corr = __expf(ml - mnew);
        float ps = 0.0f, pv = 0.0f;
#pragma unroll
        for (int kt16 = 0; kt16 < 4; ++kt16)
            if (kt16 < ktlim) {
                const float4 vv = *(const float4*)(Vg + k0 + kt16 * 16 + g * 4);
                const float e0 = __expf(acc[kt16][0] - mnew);
                const float e1 = __expf(acc[kt16][1] - mnew);
                const float e2 = __expf(acc[kt16][2] - mnew);
                const float e3 = __expf(acc[kt16][3] - mnew);
                ps += (e0 + e1) + (e2 + e3);
                pv = fmaf(e0, vv.x, fmaf(e1, vv.y, fmaf(e2, vv.z, fmaf(e3, vv.w, pv))));
            }
        ps += __shfl_xor(ps, 16); ps += __shfl_xor(ps, 32);
        pv += __shfl_xor(pv, 16); pv += __shfl_xor(pv, 32);
        ll = ll * corr + ps;
        oo = oo * corr + pv;
        ml = mnew;

        // write next tile into the other buffer, then one barrier
        if (kt < 12) {
#pragma unroll
            for (int c = 0; c < 4; ++c) {
                const int sl = sc * 4 + c;
                *(float4*)&Ks[cur ^ 1][sr * INTER + ((sl ^ (sr & 7)) << 3)] = stg[c];
            }
        }
        __syncthreads();
        cur ^= 1;
    }

    const int q = q0 + w * 16 + ql;
    if (g == 0 && q < HW)
        maskbuf[n * HW + q] = oo / ll;
}

// ---------------------------------------------------------------------------
// Kernel 3: bilinear x8 upsample (half-pixel, edge clamp) + sigmoid +
// concat([1-m, m]).
// ---------------------------------------------------------------------------
__global__ __launch_bounds__(256) void upsample_kernel(
    const float* __restrict__ maskbuf, float* __restrict__ out)
{
    const int gid = blockIdx.x * 256 + threadIdx.x;   // 64*224*56 = 802816
    const int n  = gid / (224 * 56);
    const int r  = gid - n * (224 * 56);
    const int oy = r / 56;
    const int xq = r - oy * 56;

    const float iy = (oy + 0.5f) * 0.125f - 0.5f;
    const int   y0 = (int)floorf(iy);
    const float fy = iy - (float)y0;
    const int y0c = max(y0, 0), y1c = min(y0 + 1, HH - 1);
    const float* mrow = maskbuf + n * HW;

    float res[4];
#pragma unroll
    for (int j = 0; j < 4; ++j) {
        const int   ox = (xq << 2) + j;
        const float ix = (ox + 0.5f) * 0.125f - 0.5f;
        const int   x0 = (int)floorf(ix);
        const float fx = ix - (float)x0;
        const int x0c = max(x0, 0), x1c = min(x0 + 1, WW - 1);
        const float v00 = mrow[y0c * WW + x0c], v01 = mrow[y0c * WW + x1c];
        const float v10 = mrow[y1c * WW + x0c], v11 = mrow[y1c * WW + x1c];
        const float m = (v00 * (1.0f - fx) + v01 * fx) * (1.0f - fy)
                      + (v10 * (1.0f - fx) + v11 * fx) * fy;
        res[j] = 1.0f / (1.0f + __expf(-m));
    }

    float4 pos = make_float4(res[0], res[1], res[2], res[3]);
    float4 neg = make_float4(1.0f - res[0], 1.0f - res[1],
                             1.0f - res[2], 1.0f - res[3]);
    const size_t base = (size_t)n * 2 * 50176 + (size_t)oy * 224 + (xq << 2);
    *(float4*)(out + base)         = neg;   // channel 0: 1 - mask
    *(float4*)(out + base + 50176) = pos;   // channel 1: mask
}

// ---------------------------------------------------------------------------
extern "C" void kernel_launch(void* const* d_in, const int* in_sizes, int n_in,
                              void* d_out, int out_size, void* d_ws, size_t ws_size,
                              hipStream_t stream) {
    const float* x     = (const float*)d_in[0];
    // d_in[1] = lam (unused by the reference output)
    const int*   index = (const int*)d_in[2];
    const float* Wq    = (const float*)d_in[3];
    const float* bq    = (const float*)d_in[4];
    const float* Wv    = (const float*)d_in[5];
    const float* bv    = (const float*)d_in[6];
    // d_in[7] = scale_factor (fixed = 8)

    float* out = (float*)d_out;
    // Yb (bf16, 64*784*128 = 12.8 MB) lives in d_out (25.7 MB); kernel 3
    // fully overwrites d_out afterwards.
    unsigned short* Yb = (unsigned short*)d_out;
    // ws: vAll (64*784 f32) + mask (64*784 f32) = 401,408 B
    float* vAll  = (float*)d_ws;
    float* maskb = vAll + NB * HW;

    proj_kernel<<<dim3(196, 4), 256, 0, stream>>>(x, Wq, bq, Wv, bv, Yb, vAll);
    attn_kernel<<<dim3(NB, 13), 256, 0, stream>>>(Yb, vAll, index, maskb);
    upsample_kernel<<<3136, 256, 0, stream>>>(maskb, out);
}

// Round 3
// 78.126 us; speedup vs baseline: 6.6814x; 2.6247x over previous
//
#include <hip/hip_runtime.h>
#include <math.h>

// Sizes fixed by the reference
#define NB    64
#define CIN   256
#define HH    28
#define WW    28
#define HW    784          // 28*28
#define INTER 128

typedef __bf16 bf16x8 __attribute__((ext_vector_type(8)));
typedef float  f32x4  __attribute__((ext_vector_type(4)));

#define SCALE 0.29730177875068026f   // 128^(-1/4), applied to both q and k

// round-to-nearest-even f32 -> bf16 bits
__device__ __forceinline__ unsigned int bfbits(float f) {
    unsigned int u = __builtin_bit_cast(unsigned int, f);
    return (u + 0x7fffu + ((u >> 16) & 1u)) >> 16;
}
__device__ __forceinline__ float bf2f(unsigned int bits) {
    return __builtin_bit_cast(float, bits << 16);
}

// ---------------------------------------------------------------------------
// Kernel 0: convert S*Wq to bf16 hi/lo pair, stored FRAGMENT-MAJOR so the
// proj kernel's B-operand loads are fully coalesced bf16x8 per lane:
//   element e = ((s*8 + it)*64 + l)*8 + j   maps to
//   i = it*16 + (l&15),  c = s*32 + ((l>>4)&3)*8 + j
// ---------------------------------------------------------------------------
__global__ __launch_bounds__(256) void initw_kernel(
    const float* __restrict__ Wq,
    unsigned short* __restrict__ Wbh, unsigned short* __restrict__ Wbl)
{
    const int e  = blockIdx.x * 256 + threadIdx.x;   // 0 .. 32767
    const int j  = e & 7;
    const int l  = (e >> 3) & 63;
    const int it = (e >> 9) & 7;
    const int s  = e >> 12;
    const int i  = it * 16 + (l & 15);
    const int c  = s * 32 + ((l >> 4) & 3) * 8 + j;
    const float v = Wq[i * CIN + c] * SCALE;
    const unsigned int hb = bfbits(v);
    Wbh[e] = (unsigned short)hb;
    Wbl[e] = (unsigned short)bfbits(v - bf2f(hb));
}

// ---------------------------------------------------------------------------
// Kernel 1: projection as an all-register MFMA GEMM.
//   Yb[n,p,i] = bf16( sum_c (S*Wq[i,c])*X[n,c,p] + S*bq[i] )
//   vAll[n,p] = sum_c Wv[c]*X[n,c,p] + bv
// Block = (ptile, n), 4 waves; wave w owns p-rows p0 = ptile*64 + w*16.
// A-frag (X): lane l -> row p = p0+(l&15), k = c0+(l>>4)*8+j, gathered
// directly from global (16 consecutive p per 16-lane group = 64B segments).
// x is split hi+lo bf16; W is hi+lo -> acc += xh*wh + xh*wl + xl*wh gives
// fp32-grade accuracy. No LDS, no barriers.
// ---------------------------------------------------------------------------
__global__ __launch_bounds__(256) void proj_kernel(
    const float* __restrict__ x,
    const bf16x8* __restrict__ Wfh, const bf16x8* __restrict__ Wfl,
    const float* __restrict__ bq,
    const float* __restrict__ Wv, const float* __restrict__ bv,
    unsigned short* __restrict__ Yb, float* __restrict__ vAll)
{
    const int ptile = blockIdx.x;       // 0..12
    const int n     = blockIdx.y;       // 0..63
    const int t     = threadIdx.x;
    const int l     = t & 63;
    const int w     = t >> 6;
    const int p0    = ptile * 64 + w * 16;
    const int pl    = l & 15;
    const int g     = l >> 4;           // 0..3 (k-group)

    const int pa = min(p0 + pl, HW - 1);              // A-row (clamped)
    const float* xbase = x + (size_t)n * (CIN * HW) + pa;

    f32x4 acc[8];
#pragma unroll
    for (int it = 0; it < 8; ++it) acc[it] = (f32x4){0.f, 0.f, 0.f, 0.f};
    float vpart = 0.0f;

    for (int s = 0; s < 8; ++s) {                     // K-step: 32 c
        const int c0 = s * 32 + g * 8;
        const float* xp = xbase + (size_t)c0 * HW;
        float xv[8];
#pragma unroll
        for (int j = 0; j < 8; ++j) xv[j] = xp[(size_t)j * HW];

        // fused v-projection on the same x values
        const float4 wv0 = *(const float4*)(Wv + c0);
        const float4 wv1 = *(const float4*)(Wv + c0 + 4);
        vpart = fmaf(xv[0], wv0.x, fmaf(xv[1], wv0.y,
                fmaf(xv[2], wv0.z, fmaf(xv[3], wv0.w, vpart))));
        vpart = fmaf(xv[4], wv1.x, fmaf(xv[5], wv1.y,
                fmaf(xv[6], wv1.z, fmaf(xv[7], wv1.w, vpart))));

        // split x into bf16 hi + lo
        bf16x8 ah, al;
#pragma unroll
        for (int j = 0; j < 8; ++j) {
            const float h = (float)(__bf16)xv[j];
            ah[j] = (__bf16)xv[j];
            al[j] = (__bf16)(xv[j] - h);
        }

        const int fb = s * 8 * 64 + l;                // fragment base for this wave
#pragma unroll
        for (int it = 0; it < 8; ++it) {
            const bf16x8 wh = Wfh[fb + it * 64];
            const bf16x8 wl = Wfl[fb + it * 64];
            acc[it] = __builtin_amdgcn_mfma_f32_16x16x32_bf16(ah, wh, acc[it], 0, 0, 0);
            acc[it] = __builtin_amdgcn_mfma_f32_16x16x32_bf16(ah, wl, acc[it], 0, 0, 0);
            acc[it] = __builtin_amdgcn_mfma_f32_16x16x32_bf16(al, wh, acc[it], 0, 0, 0);
        }
    }

    // v: combine the 4 k-groups (lanes pl, pl+16, pl+32, pl+48)
    vpart += __shfl_xor(vpart, 16);
    vpart += __shfl_xor(vpart, 32);
    if (g == 0 && p0 + pl < HW)
        vAll[n * HW + p0 + pl] = vpart + bv[0];

    // epilogue: D row = p0 + g*4 + r, col i = it*16 + pl
#pragma unroll
    for (int it = 0; it < 8; ++it) {
        const int i = it * 16 + pl;
        const float bb = bq[i] * SCALE;
#pragma unroll
        for (int r = 0; r < 4; ++r) {
            const int pr = p0 + g * 4 + r;
            if (pr < HW)
                Yb[((size_t)n * HW + pr) * INTER + i] =
                    (unsigned short)bfbits(acc[it][r] + bb);
        }
    }
}

// ---------------------------------------------------------------------------
// Kernel 2: fused attention, bf16 MFMA scores + in-register online softmax.
// (unchanged from round 2 — validated)
// ---------------------------------------------------------------------------
__global__ __launch_bounds__(256) void attn_kernel(
    const unsigned short* __restrict__ Yb, const float* __restrict__ vAll,
    const int* __restrict__ index, float* __restrict__ maskbuf)
{
    __shared__ unsigned short Ks[2][64 * INTER];   // 2 x 16 KiB

    const int n   = blockIdx.x;
    const int q0  = blockIdx.y * 64;
    const int t   = threadIdx.x;
    const int l   = t & 63;
    const int w   = t >> 6;
    const int idx = index[n];

    const unsigned short* Qg = Yb + (size_t)n   * (HW * INTER);
    const unsigned short* Kg = Yb + (size_t)idx * (HW * INTER);
    const float*          Vg = vAll + (size_t)idx * HW;

    const int ql = l & 15;
    const int g  = (l >> 4) & 3;

    const int qrow = min(q0 + w * 16 + ql, HW - 1);
    bf16x8 qf[4];
#pragma unroll
    for (int ic = 0; ic < 4; ++ic)
        qf[ic] = *(const bf16x8*)(Qg + (size_t)qrow * INTER + ic * 32 + g * 8);

    const int sr = t >> 2;
    const int sc = t & 3;

    float4 stg[4];
    {
        const unsigned short* Krow = Kg + (size_t)sr * INTER;
#pragma unroll
        for (int c = 0; c < 4; ++c)
            stg[c] = *(const float4*)(Krow + (sc * 4 + c) * 8);
    }
#pragma unroll
    for (int c = 0; c < 4; ++c) {
        const int sl = sc * 4 + c;
        *(float4*)&Ks[0][sr * INTER + ((sl ^ (sr & 7)) << 3)] = stg[c];
    }
    __syncthreads();

    float ml = -1e30f, ll = 0.0f, oo = 0.0f;
    int cur = 0;

    for (int kt = 0; kt < 13; ++kt) {
        const int k0 = kt * 64;
        const int ktlim = (k0 + 64 <= HW) ? 4 : 1;

        if (kt < 12) {
            const int rr = min(k0 + 64 + sr, HW - 1);
            const unsigned short* Krow = Kg + (size_t)rr * INTER;
#pragma unroll
            for (int c = 0; c < 4; ++c)
                stg[c] = *(const float4*)(Krow + (sc * 4 + c) * 8);
        }

        f32x4 acc[4];
#pragma unroll
        for (int kt16 = 0; kt16 < 4; ++kt16) {
            if (kt16 < ktlim) {
                acc[kt16] = (f32x4){0.0f, 0.0f, 0.0f, 0.0f};
#pragma unroll
                for (int ic = 0; ic < 4; ++ic) {
                    const int krow = kt16 * 16 + ql;
                    const int sl   = ic * 4 + g;
                    const bf16x8 af = *(const bf16x8*)
                        &Ks[cur][krow * INTER + ((sl ^ (krow & 7)) << 3)];
                    acc[kt16] = __builtin_amdgcn_mfma_f32_16x16x32_bf16(
                        af, qf[ic], acc[kt16], 0, 0, 0);
                }
            }
        }

        float tm = -1e30f;
#pragma unroll
        for (int kt16 = 0; kt16 < 4; ++kt16)
            if (kt16 < ktlim) {
                tm = fmaxf(tm, fmaxf(fmaxf(acc[kt16][0], acc[kt16][1]),
                                     fmaxf(acc[kt16][2], acc[kt16][3])));
            }
        tm = fmaxf(tm, __shfl_xor(tm, 16));
        tm = fmaxf(tm, __shfl_xor(tm, 32));

        const float mnew = fmaxf(ml, tm);
        const float corr = __expf(ml - mnew);
        float ps = 0.0f, pv = 0.0f;
#pragma unroll
        for (int kt16 = 0; kt16 < 4; ++kt16)
            if (kt16 < ktlim) {
                const float4 vv = *(const float4*)(Vg + k0 + kt16 * 16 + g * 4);
                const float e0 = __expf(acc[kt16][0] - mnew);
                const float e1 = __expf(acc[kt16][1] - mnew);
                const float e2 = __expf(acc[kt16][2] - mnew);
                const float e3 = __expf(acc[kt16][3] - mnew);
                ps += (e0 + e1) + (e2 + e3);
                pv = fmaf(e0, vv.x, fmaf(e1, vv.y, fmaf(e2, vv.z, fmaf(e3, vv.w, pv))));
            }
        ps += __shfl_xor(ps, 16); ps += __shfl_xor(ps, 32);
        pv += __shfl_xor(pv, 16); pv += __shfl_xor(pv, 32);
        ll = ll * corr + ps;
        oo = oo * corr + pv;
        ml = mnew;

        if (kt < 12) {
#pragma unroll
            for (int c = 0; c < 4; ++c) {
                const int sl = sc * 4 + c;
                *(float4*)&Ks[cur ^ 1][sr * INTER + ((sl ^ (sr & 7)) << 3)] = stg[c];
            }
        }
        __syncthreads();
        cur ^= 1;
    }

    const int q = q0 + w * 16 + ql;
    if (g == 0 && q < HW)
        maskbuf[n * HW + q] = oo / ll;
}

// ---------------------------------------------------------------------------
// Kernel 3: bilinear x8 upsample (half-pixel, edge clamp) + sigmoid +
// concat([1-m, m]).
// ---------------------------------------------------------------------------
__global__ __launch_bounds__(256) void upsample_kernel(
    const float* __restrict__ maskbuf, float* __restrict__ out)
{
    const int gid = blockIdx.x * 256 + threadIdx.x;   // 64*224*56 = 802816
    const int n  = gid / (224 * 56);
    const int r  = gid - n * (224 * 56);
    const int oy = r / 56;
    const int xq = r - oy * 56;

    const float iy = (oy + 0.5f) * 0.125f - 0.5f;
    const int   y0 = (int)floorf(iy);
    const float fy = iy - (float)y0;
    const int y0c = max(y0, 0), y1c = min(y0 + 1, HH - 1);
    const float* mrow = maskbuf + n * HW;

    float res[4];
#pragma unroll
    for (int j = 0; j < 4; ++j) {
        const int   ox = (xq << 2) + j;
        const float ix = (ox + 0.5f) * 0.125f - 0.5f;
        const int   x0 = (int)floorf(ix);
        const float fx = ix - (float)x0;
        const int x0c = max(x0, 0), x1c = min(x0 + 1, WW - 1);
        const float v00 = mrow[y0c * WW + x0c], v01 = mrow[y0c * WW + x1c];
        const float v10 = mrow[y1c * WW + x0c], v11 = mrow[y1c * WW + x1c];
        const float m = (v00 * (1.0f - fx) + v01 * fx) * (1.0f - fy)
                      + (v10 * (1.0f - fx) + v11 * fx) * fy;
        res[j] = 1.0f / (1.0f + __expf(-m));
    }

    float4 pos = make_float4(res[0], res[1], res[2], res[3]);
    float4 neg = make_float4(1.0f - res[0], 1.0f - res[1],
                             1.0f - res[2], 1.0f - res[3]);
    const size_t base = (size_t)n * 2 * 50176 + (size_t)oy * 224 + (xq << 2);
    *(float4*)(out + base)         = neg;   // channel 0: 1 - mask
    *(float4*)(out + base + 50176) = pos;   // channel 1: mask
}

// ---------------------------------------------------------------------------
extern "C" void kernel_launch(void* const* d_in, const int* in_sizes, int n_in,
                              void* d_out, int out_size, void* d_ws, size_t ws_size,
                              hipStream_t stream) {
    const float* x     = (const float*)d_in[0];
    // d_in[1] = lam (unused by the reference output)
    const int*   index = (const int*)d_in[2];
    const float* Wq    = (const float*)d_in[3];
    const float* bq    = (const float*)d_in[4];
    const float* Wv    = (const float*)d_in[5];
    const float* bv    = (const float*)d_in[6];
    // d_in[7] = scale_factor (fixed = 8)

    float* out = (float*)d_out;
    // d_out layout during the pipeline (25,690,112 B total):
    //   [0, 12845056)        Yb   bf16[64][784][128]
    //   [12845056, +65536)   Wbh  bf16 fragment-major (32768)
    //   [+65536, +131072)    Wbl
    // upsample_kernel fully overwrites d_out afterwards.
    unsigned short* Yb  = (unsigned short*)d_out;
    unsigned short* Wbh = Yb + (size_t)NB * HW * INTER;          // 6,422,528
    unsigned short* Wbl = Wbh + 32768;
    // ws: vAll (64*784 f32) + mask (64*784 f32) = 401,408 B
    float* vAll  = (float*)d_ws;
    float* maskb = vAll + NB * HW;

    initw_kernel<<<128, 256, 0, stream>>>(Wq, Wbh, Wbl);
    proj_kernel<<<dim3(13, NB), 256, 0, stream>>>(
        x, (const bf16x8*)Wbh, (const bf16x8*)Wbl, bq, Wv, bv, Yb, vAll);
    attn_kernel<<<dim3(NB, 13), 256, 0, stream>>>(Yb, vAll, index, maskb);
    upsample_kernel<<<3136, 256, 0, stream>>>(maskb, out);
}

// Round 4
// 77.055 us; speedup vs baseline: 6.7744x; 1.0139x over previous
//
#include <hip/hip_runtime.h>
#include <math.h>

// Sizes fixed by the reference
#define NB    64
#define CIN   256
#define HH    28
#define WW    28
#define HW    784          // 28*28
#define INTER 128

typedef __bf16 bf16x8 __attribute__((ext_vector_type(8)));
typedef float  f32x4  __attribute__((ext_vector_type(4)));

#define SCALE 0.29730177875068026f   // 128^(-1/4), applied to both q and k

#define GLB(p) ((const __attribute__((address_space(1))) void*)(p))
#define LDSP(p) ((__attribute__((address_space(3))) void*)(p))

// round-to-nearest-even f32 -> bf16 bits
__device__ __forceinline__ unsigned int bfbits(float f) {
    unsigned int u = __builtin_bit_cast(unsigned int, f);
    return (u + 0x7fffu + ((u >> 16) & 1u)) >> 16;
}
__device__ __forceinline__ float bf2f(unsigned int bits) {
    return __builtin_bit_cast(float, bits << 16);
}

// ---------------------------------------------------------------------------
// Kernel 0: convert S*Wq to bf16 hi/lo pair, stored FRAGMENT-MAJOR so the
// proj kernel's B-operand loads are fully coalesced bf16x8 per lane:
//   element e = ((s*8 + it)*64 + l)*8 + j   maps to
//   i = it*16 + (l&15),  c = s*32 + ((l>>4)&3)*8 + j
// ---------------------------------------------------------------------------
__global__ __launch_bounds__(256) void initw_kernel(
    const float* __restrict__ Wq,
    unsigned short* __restrict__ Wbh, unsigned short* __restrict__ Wbl)
{
    const int e  = blockIdx.x * 256 + threadIdx.x;   // 0 .. 32767
    const int j  = e & 7;
    const int l  = (e >> 3) & 63;
    const int it = (e >> 9) & 7;
    const int s  = e >> 12;
    const int i  = it * 16 + (l & 15);
    const int c  = s * 32 + ((l >> 4) & 3) * 8 + j;
    const float v = Wq[i * CIN + c] * SCALE;
    const unsigned int hb = bfbits(v);
    Wbh[e] = (unsigned short)hb;
    Wbl[e] = (unsigned short)bfbits(v - bf2f(hb));
}

// ---------------------------------------------------------------------------
// Kernel 1: projection as an MFMA GEMM with global_load_lds-staged X.
//   Yb[n,p,i] = bf16( sum_c (S*Wq[i,c])*X[n,c,p] + S*bq[i] )
//   vAll[n,p] = sum_c Wv[c]*X[n,c,p] + bv
// Block = (ptile, n), 4 waves; wave w owns p-rows ptile*64 + w*16 + [0,16).
// X tile [32 c][64 p] f32 (8 KB) double-buffered via global_load_lds
// dwordx4 (2 issues/wave/step, 1KB contiguous HBM requests). LDS 16B chunks
// are XOR-swizzled (slot = (p>>2) ^ ((row>>3)<<2)) applied identically on
// the pre-swizzled GLOBAL source and on the ds_read side (rule: both sides
// or neither), giving 2-way (= free) bank aliasing on reads.
// Precision: 2-MFMA scheme acc += bf16(x)*(wh + wl); x-rounding adds ~0.2%
// rel, same order as the unavoidable bf16 rounding of Yb itself.
// ---------------------------------------------------------------------------
__global__ __launch_bounds__(256) void proj_kernel(
    const float* __restrict__ x,
    const bf16x8* __restrict__ Wfh, const bf16x8* __restrict__ Wfl,
    const float* __restrict__ bq,
    const float* __restrict__ Wv, const float* __restrict__ bv,
    unsigned short* __restrict__ Yb, float* __restrict__ vAll)
{
    __shared__ float Xs[2][32 * 64];    // [c 32][p 64], chunk-swizzled; 2x8KB

    const int ptile = blockIdx.x;       // 0..12
    const int n     = blockIdx.y;       // 0..63
    const int t     = threadIdx.x;
    const int l     = t & 63;
    const int w     = t >> 6;
    const int pl    = l & 15;
    const int g     = l >> 4;           // 0..3 (k-group / staging row-in-quad)
    const int p0    = ptile * 64;

    const float* xn = x + (size_t)n * (CIN * HW);

    // staging: wave w stages rows w*8 .. w*8+7 of the 32-row tile.
    // lane l -> row rt = w*8 + q*4 + g, LDS slot l&15; that slot must hold
    // global chunk kk = (l&15) ^ (w<<2)   [since rt>>3 == w].
    const int kk    = pl ^ (w << 2);
    const int psrc  = min(p0 + kk * 4, HW - 4);   // clamp keeps loads in-bounds

    // reader: lane (w,pl,g) reads rows g*8+j at p = w*16+pl
    const int slot  = ((w * 16 + pl) >> 2) ^ (g << 2);
    const int rbyte = slot * 4 + (pl & 3);        // float offset within row

    f32x4 acc[8];
#pragma unroll
    for (int it = 0; it < 8; ++it) acc[it] = (f32x4){0.f, 0.f, 0.f, 0.f};
    float vpart = 0.0f;

    // prologue: stage tile 0
#pragma unroll
    for (int q = 0; q < 2; ++q) {
        const int rt = w * 8 + q * 4 + g;
        const float* src = xn + (size_t)rt * HW + psrc;
        float* dst = &Xs[0][(w * 8 + q * 4) * 64];
        __builtin_amdgcn_global_load_lds(GLB(src), LDSP(dst), 16, 0, 0);
    }
    __syncthreads();

    int cur = 0;
    for (int s = 0; s < 8; ++s) {                 // K-step: 32 c
        // issue next tile's staging (overlaps with compute below)
        if (s < 7) {
#pragma unroll
            for (int q = 0; q < 2; ++q) {
                const int rt = w * 8 + q * 4 + g;
                const float* src = xn + (size_t)((s + 1) * 32 + rt) * HW + psrc;
                float* dst = &Xs[cur ^ 1][(w * 8 + q * 4) * 64];
                __builtin_amdgcn_global_load_lds(GLB(src), LDSP(dst), 16, 0, 0);
            }
        }

        // fragment gather from LDS (2-way bank aliasing = free)
        float xv[8];
#pragma unroll
        for (int j = 0; j < 8; ++j)
            xv[j] = Xs[cur][(g * 8 + j) * 64 + rbyte];

        // fused v-projection (c = s*32 + g*8 + j)
        const float4 wv0 = *(const float4*)(Wv + s * 32 + g * 8);
        const float4 wv1 = *(const float4*)(Wv + s * 32 + g * 8 + 4);
        vpart = fmaf(xv[0], wv0.x, fmaf(xv[1], wv0.y,
                fmaf(xv[2], wv0.z, fmaf(xv[3], wv0.w, vpart))));
        vpart = fmaf(xv[4], wv1.x, fmaf(xv[5], wv1.y,
                fmaf(xv[6], wv1.z, fmaf(xv[7], wv1.w, vpart))));

        bf16x8 ah;
#pragma unroll
        for (int j = 0; j < 8; ++j) ah[j] = (__bf16)xv[j];

        const int fb = s * 8 * 64 + l;
#pragma unroll
        for (int it = 0; it < 8; ++it) {
            const bf16x8 wh = Wfh[fb + it * 64];
            const bf16x8 wl = Wfl[fb + it * 64];
            acc[it] = __builtin_amdgcn_mfma_f32_16x16x32_bf16(ah, wh, acc[it], 0, 0, 0);
            acc[it] = __builtin_amdgcn_mfma_f32_16x16x32_bf16(ah, wl, acc[it], 0, 0, 0);
        }

        __syncthreads();   // drains next-tile staging; protects buffer reuse
        cur ^= 1;
    }

    const int p0w = p0 + w * 16;

    // v: combine the 4 k-groups (lanes pl, pl+16, pl+32, pl+48)
    vpart += __shfl_xor(vpart, 16);
    vpart += __shfl_xor(vpart, 32);
    if (g == 0 && p0w + pl < HW)
        vAll[n * HW + p0w + pl] = vpart + bv[0];

    // epilogue: D row = p0w + g*4 + r, col i = it*16 + pl
#pragma unroll
    for (int it = 0; it < 8; ++it) {
        const int i = it * 16 + pl;
        const float bb = bq[i] * SCALE;
#pragma unroll
        for (int r = 0; r < 4; ++r) {
            const int pr = p0w + g * 4 + r;
            if (pr < HW)
                Yb[((size_t)n * HW + pr) * INTER + i] =
                    (unsigned short)bfbits(acc[it][r] + bb);
        }
    }
}

// ---------------------------------------------------------------------------
// Kernel 2: fused attention, bf16 MFMA scores + in-register online softmax.
// (unchanged — validated rounds 2-3)
// ---------------------------------------------------------------------------
__global__ __launch_bounds__(256) void attn_kernel(
    const unsigned short* __restrict__ Yb, const float* __restrict__ vAll,
    const int* __restrict__ index, float* __restrict__ maskbuf)
{
    __shared__ unsigned short Ks[2][64 * INTER];   // 2 x 16 KiB

    const int n   = blockIdx.x;
    const int q0  = blockIdx.y * 64;
    const int t   = threadIdx.x;
    const int l   = t & 63;
    const int w   = t >> 6;
    const int idx = index[n];

    const unsigned short* Qg = Yb + (size_t)n   * (HW * INTER);
    const unsigned short* Kg = Yb + (size_t)idx * (HW * INTER);
    const float*          Vg = vAll + (size_t)idx * HW;

    const int ql = l & 15;
    const int g  = (l >> 4) & 3;

    const int qrow = min(q0 + w * 16 + ql, HW - 1);
    bf16x8 qf[4];
#pragma unroll
    for (int ic = 0; ic < 4; ++ic)
        qf[ic] = *(const bf16x8*)(Qg + (size_t)qrow * INTER + ic * 32 + g * 8);

    const int sr = t >> 2;
    const int sc = t & 3;

    float4 stg[4];
    {
        const unsigned short* Krow = Kg + (size_t)sr * INTER;
#pragma unroll
        for (int c = 0; c < 4; ++c)
            stg[c] = *(const float4*)(Krow + (sc * 4 + c) * 8);
    }
#pragma unroll
    for (int c = 0; c < 4; ++c) {
        const int sl = sc * 4 + c;
        *(float4*)&Ks[0][sr * INTER + ((sl ^ (sr & 7)) << 3)] = stg[c];
    }
    __syncthreads();

    float ml = -1e30f, ll = 0.0f, oo = 0.0f;
    int cur = 0;

    for (int kt = 0; kt < 13; ++kt) {
        const int k0 = kt * 64;
        const int ktlim = (k0 + 64 <= HW) ? 4 : 1;

        if (kt < 12) {
            const int rr = min(k0 + 64 + sr, HW - 1);
            const unsigned short* Krow = Kg + (size_t)rr * INTER;
#pragma unroll
            for (int c = 0; c < 4; ++c)
                stg[c] = *(const float4*)(Krow + (sc * 4 + c) * 8);
        }

        f32x4 acc[4];
#pragma unroll
        for (int kt16 = 0; kt16 < 4; ++kt16) {
            if (kt16 < ktlim) {
                acc[kt16] = (f32x4){0.0f, 0.0f, 0.0f, 0.0f};
#pragma unroll
                for (int ic = 0; ic < 4; ++ic) {
                    const int krow = kt16 * 16 + ql;
                    const int sl   = ic * 4 + g;
                    const bf16x8 af = *(const bf16x8*)
                        &Ks[cur][krow * INTER + ((sl ^ (krow & 7)) << 3)];
                    acc[kt16] = __builtin_amdgcn_mfma_f32_16x16x32_bf16(
                        af, qf[ic], acc[kt16], 0, 0, 0);
                }
            }
        }

        float tm = -1e30f;
#pragma unroll
        for (int kt16 = 0; kt16 < 4; ++kt16)
            if (kt16 < ktlim) {
                tm = fmaxf(tm, fmaxf(fmaxf(acc[kt16][0], acc[kt16][1]),
                                     fmaxf(acc[kt16][2], acc[kt16][3])));
            }
        tm = fmaxf(tm, __shfl_xor(tm, 16));
        tm = fmaxf(tm, __shfl_xor(tm, 32));

        const float mnew = fmaxf(ml, tm);
        const float corr = __expf(ml - mnew);
        float ps = 0.0f, pv = 0.0f;
#pragma unroll
        for (int kt16 = 0; kt16 < 4; ++kt16)
            if (kt16 < ktlim) {
                const float4 vv = *(const float4*)(Vg + k0 + kt16 * 16 + g * 4);
                const float e0 = __expf(acc[kt16][0] - mnew);
                const float e1 = __expf(acc[kt16][1] - mnew);
                const float e2 = __expf(acc[kt16][2] - mnew);
                const float e3 = __expf(acc[kt16][3] - mnew);
                ps += (e0 + e1) + (e2 + e3);
                pv = fmaf(e0, vv.x, fmaf(e1, vv.y, fmaf(e2, vv.z, fmaf(e3, vv.w, pv))));
            }
        ps += __shfl_xor(ps, 16); ps += __shfl_xor(ps, 32);
        pv += __shfl_xor(pv, 16); pv += __shfl_xor(pv, 32);
        ll = ll * corr + ps;
        oo = oo * corr + pv;
        ml = mnew;

        if (kt < 12) {
#pragma unroll
            for (int c = 0; c < 4; ++c) {
                const int sl = sc * 4 + c;
                *(float4*)&Ks[cur ^ 1][sr * INTER + ((sl ^ (sr & 7)) << 3)] = stg[c];
            }
        }
        __syncthreads();
        cur ^= 1;
    }

    const int q = q0 + w * 16 + ql;
    if (g == 0 && q < HW)
        maskbuf[n * HW + q] = oo / ll;
}

// ---------------------------------------------------------------------------
// Kernel 3: bilinear x8 upsample (half-pixel, edge clamp) + sigmoid +
// concat([1-m, m]).
// ---------------------------------------------------------------------------
__global__ __launch_bounds__(256) void upsample_kernel(
    const float* __restrict__ maskbuf, float* __restrict__ out)
{
    const int gid = blockIdx.x * 256 + threadIdx.x;   // 64*224*56 = 802816
    const int n  = gid / (224 * 56);
    const int r  = gid - n * (224 * 56);
    const int oy = r / 56;
    const int xq = r - oy * 56;

    const float iy = (oy + 0.5f) * 0.125f - 0.5f;
    const int   y0 = (int)floorf(iy);
    const float fy = iy - (float)y0;
    const int y0c = max(y0, 0), y1c = min(y0 + 1, HH - 1);
    const float* mrow = maskbuf + n * HW;

    float res[4];
#pragma unroll
    for (int j = 0; j < 4; ++j) {
        const int   ox = (xq << 2) + j;
        const float ix = (ox + 0.5f) * 0.125f - 0.5f;
        const int   x0 = (int)floorf(ix);
        const float fx = ix - (float)x0;
        const int x0c = max(x0, 0), x1c = min(x0 + 1, WW - 1);
        const float v00 = mrow[y0c * WW + x0c], v01 = mrow[y0c * WW + x1c];
        const float v10 = mrow[y1c * WW + x0c], v11 = mrow[y1c * WW + x1c];
        const float m = (v00 * (1.0f - fx) + v01 * fx) * (1.0f - fy)
                      + (v10 * (1.0f - fx) + v11 * fx) * fy;
        res[j] = 1.0f / (1.0f + __expf(-m));
    }

    float4 pos = make_float4(res[0], res[1], res[2], res[3]);
    float4 neg = make_float4(1.0f - res[0], 1.0f - res[1],
                             1.0f - res[2], 1.0f - res[3]);
    const size_t base = (size_t)n * 2 * 50176 + (size_t)oy * 224 + (xq << 2);
    *(float4*)(out + base)         = neg;   // channel 0: 1 - mask
    *(float4*)(out + base + 50176) = pos;   // channel 1: mask
}

// ---------------------------------------------------------------------------
extern "C" void kernel_launch(void* const* d_in, const int* in_sizes, int n_in,
                              void* d_out, int out_size, void* d_ws, size_t ws_size,
                              hipStream_t stream) {
    const float* x     = (const float*)d_in[0];
    // d_in[1] = lam (unused by the reference output)
    const int*   index = (const int*)d_in[2];
    const float* Wq    = (const float*)d_in[3];
    const float* bq    = (const float*)d_in[4];
    const float* Wv    = (const float*)d_in[5];
    const float* bv    = (const float*)d_in[6];
    // d_in[7] = scale_factor (fixed = 8)

    float* out = (float*)d_out;
    // d_out layout during the pipeline (25,690,112 B total):
    //   [0, 12845056)        Yb   bf16[64][784][128]
    //   [12845056, +65536)   Wbh  bf16 fragment-major (32768)
    //   [+65536, +131072)    Wbl
    // upsample_kernel fully overwrites d_out afterwards.
    unsigned short* Yb  = (unsigned short*)d_out;
    unsigned short* Wbh = Yb + (size_t)NB * HW * INTER;          // 6,422,528
    unsigned short* Wbl = Wbh + 32768;
    // ws: vAll (64*784 f32) + mask (64*784 f32) = 401,408 B
    float* vAll  = (float*)d_ws;
    float* maskb = vAll + NB * HW;

    initw_kernel<<<128, 256, 0, stream>>>(Wq, Wbh, Wbl);
    proj_kernel<<<dim3(13, NB), 256, 0, stream>>>(
        x, (const bf16x8*)Wbh, (const bf16x8*)Wbl, bq, Wv, bv, Yb, vAll);
    attn_kernel<<<dim3(NB, 13), 256, 0, stream>>>(Yb, vAll, index, maskb);
    upsample_kernel<<<3136, 256, 0, stream>>>(maskb, out);
}